// Round 4
// baseline (121.630 us; speedup 1.0000x reference)
//
#include <hip/hip_runtime.h>

#define N_SAMPLES 4096
#define D_IN      128
#define R_RULES   256
#define O_OUT     64
#define KPAD      136
#define NCHUNK    17
#define CH_I      8
#define NGROUPS   8

typedef _Float16 f16;
typedef _Float16 f16x2 __attribute__((ext_vector_type(2)));
typedef _Float16 f16x4 __attribute__((ext_vector_type(4)));
typedef _Float16 f16x8 __attribute__((ext_vector_type(8)));
typedef float    f32x4 __attribute__((ext_vector_type(4)));

// ---------------------------------------------------------------------------
// Kernel A (unchanged): build Bext for the strengths GEMM (Markidis split).
// ---------------------------------------------------------------------------
__global__ __launch_bounds__(128) void anfis_prep2(
    const float* __restrict__ centers, const float* __restrict__ sigmas,
    f16* __restrict__ Bext) {
  const int r = blockIdx.x;
  const int d = threadIdx.x;
  const float c = centers[(size_t)r * 128 + d];
  const float s = sigmas[(size_t)r * 128 + d];
  const float iv = 0.5f / (s * s);
  const float b1 = -iv;
  const float b2 = 2.0f * c * iv;
  f16 b1h = (f16)b1; f16 b1l = (f16)(b1 - (float)b1h);
  f16 b2h = (f16)b2; f16 b2l = (f16)(b2 - (float)b2h);
  auto put = [&](int k, f16 v) {
    Bext[((size_t)(k >> 3) * 256 + r) * 8 + (k & 7)] = v;
  };
  put(d, b1h);
  put(128 + d, b1l);
  put(256 + d, b1h);
  put(384 + d, b2h);
  put(512 + d, b2l);
  put(640 + d, b2h);
  float p = -c * c * iv;
#pragma unroll
  for (int off = 32; off; off >>= 1) p += __shfl_xor(p, off, 64);
  __shared__ float red[2];
  if ((threadIdx.x & 63) == 0) red[threadIdx.x >> 6] = p;
  __syncthreads();
  if (d < 30) put(770 + d, (f16)0.0f);
  if (d == 0) {
    float k2 = red[0] + red[1];
    f16 h = (f16)k2; f16 l = (f16)(k2 - (float)h);
    put(768, h);
    put(769, l);
  }
}

// ---------------------------------------------------------------------------
// Kernel B (unchanged): strengths via MFMA, barrier-free k-loop.
// ---------------------------------------------------------------------------
__global__ __launch_bounds__(512) void anfis_s16(
    const float* __restrict__ X, const f16* __restrict__ Bext,
    float* __restrict__ S) {
  __shared__ alignas(16) f16 Xq[32 * 512];
  const int tid = threadIdx.x;
  const int m0 = (blockIdx.x >> 1) * 32;
  const int r0 = (blockIdx.x & 1) * 128;
  const int w = tid >> 6, lane = tid & 63;
  const int mg = w >> 2, ng = w & 3;
  const int lm = lane & 15, quad = lane >> 4;

  {
    int m = tid >> 4, oct = tid & 15;
    const float* src = X + (size_t)(m0 + m) * 128 + oct * 8;
    float4 a = reinterpret_cast<const float4*>(src)[0];
    float4 b = reinterpret_cast<const float4*>(src)[1];
    float xs[8] = {a.x, a.y, a.z, a.w, b.x, b.y, b.z, b.w};
    f16x8 vh, vl, v2h, v2l;
#pragma unroll
    for (int q = 0; q < 8; ++q) {
      float x = xs[q];
      f16 h = (f16)x;   f16 l = (f16)(x - (float)h);
      float x2 = x * x;
      f16 h2 = (f16)x2; f16 l2 = (f16)(x2 - (float)h2);
      vh[q] = h; vl[q] = l; v2h[q] = h2; v2l[q] = l2;
    }
    f16x8* row = reinterpret_cast<f16x8*>(&Xq[m * 512]);
    int sw = m & 7;
    row[(0 * 16 + oct) ^ sw] = v2h;
    row[(1 * 16 + oct) ^ sw] = v2l;
    row[(2 * 16 + oct) ^ sw] = vh;
    row[(3 * 16 + oct) ^ sw] = vl;
  }
  __syncthreads();

  f32x4 acc[2] = {};
  const int am = mg * 16 + lm;
  const f16x8* arow = reinterpret_cast<const f16x8*>(&Xq[am * 512]);
  const int asw = am & 7;
  const int col0 = r0 + ng * 32 + lm;

#pragma unroll
  for (int t = 0; t < 24; ++t) {
    const int seg = t >> 2;
    const int plane = (seg < 2) ? 0 : (seg == 2) ? 1 : (seg < 5) ? 2 : 3;
    const int o = t * 4 + quad;
    f16x8 av = arow[(plane * 16 + (o & 15)) ^ asw];
    const f16* bp = Bext + ((size_t)o * 256 + col0) * 8;
    f16x8 b0 = *reinterpret_cast<const f16x8*>(bp);
    f16x8 b1 = *reinterpret_cast<const f16x8*>(bp + 16 * 8);
    acc[0] = __builtin_amdgcn_mfma_f32_16x16x32_f16(av, b0, acc[0], 0, 0, 0);
    acc[1] = __builtin_amdgcn_mfma_f32_16x16x32_f16(av, b1, acc[1], 0, 0, 0);
  }
  {
    f16x8 av = {};
    if (quad == 0) { av[0] = (f16)1.0f; av[1] = (f16)1.0f; }
    const int o = 96 + quad;
    const f16* bp = Bext + ((size_t)o * 256 + col0) * 8;
    f16x8 b0 = *reinterpret_cast<const f16x8*>(bp);
    f16x8 b1 = *reinterpret_cast<const f16x8*>(bp + 16 * 8);
    acc[0] = __builtin_amdgcn_mfma_f32_16x16x32_f16(av, b0, acc[0], 0, 0, 0);
    acc[1] = __builtin_amdgcn_mfma_f32_16x16x32_f16(av, b1, acc[1], 0, 0, 0);
  }
#pragma unroll
  for (int nf = 0; nf < 2; ++nf)
#pragma unroll
    for (int q = 0; q < 4; ++q) {
      int row = m0 + mg * 16 + quad * 4 + q;
      int col = r0 + ng * 32 + nf * 16 + lm;
      S[(size_t)row * R_RULES + col] = __expf(acc[nf][q]);
    }
}

// ---------------------------------------------------------------------------
// Kernel C: inv-denominator only (normalization folded into main16).
// ---------------------------------------------------------------------------
__global__ __launch_bounds__(256) void anfis_den(
    const float* __restrict__ S, float* __restrict__ invden) {
  const int n = blockIdx.x * 4 + (threadIdx.x >> 6);
  const int lane = threadIdx.x & 63;
  float4 v = reinterpret_cast<const float4*>(S)[(size_t)n * 64 + lane];
  float s = (v.x + v.y) + (v.z + v.w);
#pragma unroll
  for (int off = 32; off; off >>= 1) s += __shfl_xor(s, off, 64);
  if (lane == 0) invden[n] = 1.0f / (s + 1e-8f);
}

// ---------------------------------------------------------------------------
// Kernel D (unchanged): permute coeffs fp32 -> fp16 Cp[g][c][ii][j][rg].
// ---------------------------------------------------------------------------
__global__ __launch_bounds__(256) void anfis_prep(
    const float* __restrict__ coeffs, f16* __restrict__ Cp) {
  __shared__ alignas(16) f16 T[64 * 32];
  const int i = blockIdx.x;
  const int g = blockIdx.y;
  const int tid = threadIdx.x;
  const int rg = tid & 31;
  const int jb = tid >> 5;
  if (i < 129) {
    const float* src = coeffs + ((size_t)(g * 32 + rg) * 129 + i) * 64 + jb * 8;
    float4 a = reinterpret_cast<const float4*>(src)[0];
    float4 b = reinterpret_cast<const float4*>(src)[1];
    T[(jb * 8 + 0) * 32 + rg] = (f16)a.x;
    T[(jb * 8 + 1) * 32 + rg] = (f16)a.y;
    T[(jb * 8 + 2) * 32 + rg] = (f16)a.z;
    T[(jb * 8 + 3) * 32 + rg] = (f16)a.w;
    T[(jb * 8 + 4) * 32 + rg] = (f16)b.x;
    T[(jb * 8 + 5) * 32 + rg] = (f16)b.y;
    T[(jb * 8 + 6) * 32 + rg] = (f16)b.z;
    T[(jb * 8 + 7) * 32 + rg] = (f16)b.w;
  } else {
#pragma unroll
    for (int q = 0; q < 8; ++q) T[(jb * 8 + q) * 32 + rg] = (f16)0.0f;
  }
  __syncthreads();
  f16x8* dst = reinterpret_cast<f16x8*>(
      Cp + (((size_t)g * NCHUNK + (i >> 3)) * CH_I + (i & 7)) * 2048);
  dst[tid] = reinterpret_cast<const f16x8*>(T)[tid];
}

// ---------------------------------------------------------------------------
// Kernel E v2: rules GEMM, BARRIER-FREE k-loop.  B-frags read directly from
// L2-resident Cp (g-slice 557KB, g=bid&7 XCD affinity; mg-duplication hits
// L1).  LDS holds only the X tile (17KB -> ~5 blocks/CU vs 2 before).  The
// normalization is folded in: pf = S * invden.
// ---------------------------------------------------------------------------
__global__ __launch_bounds__(256) void anfis_main16(
    const float* __restrict__ X, const float* __restrict__ S,
    const float* __restrict__ invden, const f16* __restrict__ Cp,
    float* __restrict__ part) {
  __shared__ alignas(16) f16 Xs[64 * KPAD];          // [m][i], 17408 B
  const int tid = threadIdx.x;
  const int g = blockIdx.x & 7;
  const int m0 = (blockIdx.x >> 3) * 64;
  const int w = tid >> 6, lane = tid & 63;
  const int mg = w >> 1, ng = w & 1;
  const int lm = lane & 15, quad = lane >> 4;

#pragma unroll
  for (int it = 0; it < 8; ++it) {
    int fi = tid + (it << 8);
    int m = fi >> 5, k4 = (fi & 31) << 2;
    float4 v = reinterpret_cast<const float4*>(X)[(size_t)(m0 + m) * 32 + (fi & 31)];
    f16x4 h = {(f16)v.x, (f16)v.y, (f16)v.z, (f16)v.w};
    *reinterpret_cast<f16x4*>(&Xs[m * KPAD + k4]) = h;
  }
  if (tid < 64) {
    f16x8 bias = {};
    bias[0] = (f16)1.0f;
    *reinterpret_cast<f16x8*>(&Xs[tid * KPAD + 128]) = bias;
  }

  union F8 { f16x8 v; f16x2 h[4]; };
  F8 pf[2];
#pragma unroll
  for (int mf = 0; mf < 2; ++mf) {
    int row = m0 + mg * 32 + mf * 16 + lm;
    const float invd = invden[row];
    const float* pp = S + (size_t)row * R_RULES + g * 32 + quad * 8;
    float4 p0 = reinterpret_cast<const float4*>(pp)[0];
    float4 p1 = reinterpret_cast<const float4*>(pp)[1];
    pf[mf].h[0] = f16x2{(f16)(p0.x * invd), (f16)(p0.y * invd)};
    pf[mf].h[1] = f16x2{(f16)(p0.z * invd), (f16)(p0.w * invd)};
    pf[mf].h[2] = f16x2{(f16)(p1.x * invd), (f16)(p1.y * invd)};
    pf[mf].h[3] = f16x2{(f16)(p1.z * invd), (f16)(p1.w * invd)};
  }
  __syncthreads();

  f32x4 acc[2][2] = {};
  // lane's B pointer within the g-slice: [c][ii][j=ng*32+lm][rg: quad*8..+7]
  const f16* bpl = Cp + (size_t)g * NCHUNK * CH_I * 2048
                 + ((ng * 32 + lm) * 32 + quad * 8);

  for (int c = 0; c < NCHUNK; ++c) {
    f16x8 xv[2];
    xv[0] = *reinterpret_cast<const f16x8*>(&Xs[(mg * 32 + lm) * KPAD + c * 8]);
    xv[1] = *reinterpret_cast<const f16x8*>(&Xs[(mg * 32 + 16 + lm) * KPAD + c * 8]);
    const f16* bpc = bpl + (size_t)c * (CH_I * 2048);
#pragma unroll
    for (int ii = 0; ii < CH_I; ++ii) {
      f16x8 b0 = *reinterpret_cast<const f16x8*>(bpc + ii * 2048);
      f16x8 b1 = *reinterpret_cast<const f16x8*>(bpc + ii * 2048 + 512);
      F8 a[2];
#pragma unroll
      for (int mf = 0; mf < 2; ++mf) {
        f16 xvv = xv[mf][ii];
        f16x2 xd = {xvv, xvv};
        a[mf].h[0] = pf[mf].h[0] * xd;
        a[mf].h[1] = pf[mf].h[1] * xd;
        a[mf].h[2] = pf[mf].h[2] * xd;
        a[mf].h[3] = pf[mf].h[3] * xd;
      }
      acc[0][0] = __builtin_amdgcn_mfma_f32_16x16x32_f16(a[0].v, b0, acc[0][0], 0, 0, 0);
      acc[0][1] = __builtin_amdgcn_mfma_f32_16x16x32_f16(a[0].v, b1, acc[0][1], 0, 0, 0);
      acc[1][0] = __builtin_amdgcn_mfma_f32_16x16x32_f16(a[1].v, b0, acc[1][0], 0, 0, 0);
      acc[1][1] = __builtin_amdgcn_mfma_f32_16x16x32_f16(a[1].v, b1, acc[1][1], 0, 0, 0);
    }
  }

#pragma unroll
  for (int mf = 0; mf < 2; ++mf)
#pragma unroll
    for (int nf = 0; nf < 2; ++nf)
#pragma unroll
      for (int q = 0; q < 4; ++q) {
        int row = m0 + mg * 32 + mf * 16 + quad * 4 + q;
        int col = ng * 32 + nf * 16 + lm;
        part[((size_t)g * N_SAMPLES + row) * O_OUT + col] = acc[mf][nf][q];
      }
}

// ---------------------------------------------------------------------------
// Kernel F (unchanged): sum 8 group partials + softmax over 64 outputs.
// ---------------------------------------------------------------------------
__global__ __launch_bounds__(256) void anfis_out(
    const float* __restrict__ part, float* __restrict__ out) {
  const int n = blockIdx.x * 4 + (threadIdx.x >> 6);
  const int lane = threadIdx.x & 63;
  const size_t stride = (size_t)N_SAMPLES * O_OUT;
  const float* p0 = part + (size_t)n * O_OUT + lane;
  float v = 0.f;
#pragma unroll
  for (int gg = 0; gg < 8; ++gg) v += p0[gg * stride];
  float mx = v;
#pragma unroll
  for (int off = 32; off; off >>= 1) mx = fmaxf(mx, __shfl_xor(mx, off, 64));
  float e = __expf(v - mx);
  float s = e;
#pragma unroll
  for (int off = 32; off; off >>= 1) s += __shfl_xor(s, off, 64);
  out[(size_t)n * O_OUT + lane] = e / s;
}

extern "C" void kernel_launch(void* const* d_in, const int* in_sizes, int n_in,
                              void* d_out, int out_size, void* d_ws, size_t ws_size,
                              hipStream_t stream) {
  const float* X       = (const float*)d_in[0];
  const float* centers = (const float*)d_in[1];
  const float* sigmas  = (const float*)d_in[2];
  const float* coeffs  = (const float*)d_in[3];
  float* out = (float*)d_out;

  float* S    = (float*)d_ws;                                   // 4 MB
  float* part = S + (size_t)N_SAMPLES * R_RULES;                // 8 MB
  f16*   Cp   = (f16*)(part + (size_t)NGROUPS * N_SAMPLES * O_OUT);
  f16*   Bext = Cp + (size_t)NGROUPS * NCHUNK * CH_I * 2048;    // 400 KB
  float* invden = (float*)(Bext + (size_t)100 * 256 * 8);       // 16 KB

  anfis_prep2<<<R_RULES, 128, 0, stream>>>(centers, sigmas, Bext);
  anfis_prep<<<dim3(KPAD, NGROUPS), 256, 0, stream>>>(coeffs, Cp);
  anfis_s16<<<256, 512, 0, stream>>>(X, Bext, S);
  anfis_den<<<N_SAMPLES / 4, 256, 0, stream>>>(S, invden);
  anfis_main16<<<512, 256, 0, stream>>>(X, S, invden, Cp, part);
  anfis_out<<<N_SAMPLES / 4, 256, 0, stream>>>(part, out);
}

// Round 5
// 115.065 us; speedup vs baseline: 1.0571x; 1.0571x over previous
//
#include <hip/hip_runtime.h>

#define N_SAMPLES 4096
#define D_IN      128
#define R_RULES   256
#define O_OUT     64
#define KPAD      136
#define NCHUNK    17   // prep-kernel chunking (8 i per chunk)
#define CH_I      8
#define CH4       4    // main16 k-chunk: 4 i-rows (16KB staged)
#define NCH4      34
#define NGROUPS   8

typedef _Float16 f16;
typedef _Float16 f16x2 __attribute__((ext_vector_type(2)));
typedef _Float16 f16x4 __attribute__((ext_vector_type(4)));
typedef _Float16 f16x8 __attribute__((ext_vector_type(8)));
typedef float    f32x4 __attribute__((ext_vector_type(4)));

// ---------------------------------------------------------------------------
// Kernel A (unchanged): build Bext for the strengths GEMM (Markidis split).
// ---------------------------------------------------------------------------
__global__ __launch_bounds__(128) void anfis_prep2(
    const float* __restrict__ centers, const float* __restrict__ sigmas,
    f16* __restrict__ Bext) {
  const int r = blockIdx.x;
  const int d = threadIdx.x;
  const float c = centers[(size_t)r * 128 + d];
  const float s = sigmas[(size_t)r * 128 + d];
  const float iv = 0.5f / (s * s);
  const float b1 = -iv;
  const float b2 = 2.0f * c * iv;
  f16 b1h = (f16)b1; f16 b1l = (f16)(b1 - (float)b1h);
  f16 b2h = (f16)b2; f16 b2l = (f16)(b2 - (float)b2h);
  auto put = [&](int k, f16 v) {
    Bext[((size_t)(k >> 3) * 256 + r) * 8 + (k & 7)] = v;
  };
  put(d, b1h);
  put(128 + d, b1l);
  put(256 + d, b1h);
  put(384 + d, b2h);
  put(512 + d, b2l);
  put(640 + d, b2h);
  float p = -c * c * iv;
#pragma unroll
  for (int off = 32; off; off >>= 1) p += __shfl_xor(p, off, 64);
  __shared__ float red[2];
  if ((threadIdx.x & 63) == 0) red[threadIdx.x >> 6] = p;
  __syncthreads();
  if (d < 30) put(770 + d, (f16)0.0f);
  if (d == 0) {
    float k2 = red[0] + red[1];
    f16 h = (f16)k2; f16 l = (f16)(k2 - (float)h);
    put(768, h);
    put(769, l);
  }
}

// ---------------------------------------------------------------------------
// Kernel B (unchanged): strengths via MFMA, barrier-free k-loop.
// ---------------------------------------------------------------------------
__global__ __launch_bounds__(512) void anfis_s16(
    const float* __restrict__ X, const f16* __restrict__ Bext,
    float* __restrict__ S) {
  __shared__ alignas(16) f16 Xq[32 * 512];
  const int tid = threadIdx.x;
  const int m0 = (blockIdx.x >> 1) * 32;
  const int r0 = (blockIdx.x & 1) * 128;
  const int w = tid >> 6, lane = tid & 63;
  const int mg = w >> 2, ng = w & 3;
  const int lm = lane & 15, quad = lane >> 4;

  {
    int m = tid >> 4, oct = tid & 15;
    const float* src = X + (size_t)(m0 + m) * 128 + oct * 8;
    float4 a = reinterpret_cast<const float4*>(src)[0];
    float4 b = reinterpret_cast<const float4*>(src)[1];
    float xs[8] = {a.x, a.y, a.z, a.w, b.x, b.y, b.z, b.w};
    f16x8 vh, vl, v2h, v2l;
#pragma unroll
    for (int q = 0; q < 8; ++q) {
      float x = xs[q];
      f16 h = (f16)x;   f16 l = (f16)(x - (float)h);
      float x2 = x * x;
      f16 h2 = (f16)x2; f16 l2 = (f16)(x2 - (float)h2);
      vh[q] = h; vl[q] = l; v2h[q] = h2; v2l[q] = l2;
    }
    f16x8* row = reinterpret_cast<f16x8*>(&Xq[m * 512]);
    int sw = m & 7;
    row[(0 * 16 + oct) ^ sw] = v2h;
    row[(1 * 16 + oct) ^ sw] = v2l;
    row[(2 * 16 + oct) ^ sw] = vh;
    row[(3 * 16 + oct) ^ sw] = vl;
  }
  __syncthreads();

  f32x4 acc[2] = {};
  const int am = mg * 16 + lm;
  const f16x8* arow = reinterpret_cast<const f16x8*>(&Xq[am * 512]);
  const int asw = am & 7;
  const int col0 = r0 + ng * 32 + lm;

#pragma unroll
  for (int t = 0; t < 24; ++t) {
    const int seg = t >> 2;
    const int plane = (seg < 2) ? 0 : (seg == 2) ? 1 : (seg < 5) ? 2 : 3;
    const int o = t * 4 + quad;
    f16x8 av = arow[(plane * 16 + (o & 15)) ^ asw];
    const f16* bp = Bext + ((size_t)o * 256 + col0) * 8;
    f16x8 b0 = *reinterpret_cast<const f16x8*>(bp);
    f16x8 b1 = *reinterpret_cast<const f16x8*>(bp + 16 * 8);
    acc[0] = __builtin_amdgcn_mfma_f32_16x16x32_f16(av, b0, acc[0], 0, 0, 0);
    acc[1] = __builtin_amdgcn_mfma_f32_16x16x32_f16(av, b1, acc[1], 0, 0, 0);
  }
  {
    f16x8 av = {};
    if (quad == 0) { av[0] = (f16)1.0f; av[1] = (f16)1.0f; }
    const int o = 96 + quad;
    const f16* bp = Bext + ((size_t)o * 256 + col0) * 8;
    f16x8 b0 = *reinterpret_cast<const f16x8*>(bp);
    f16x8 b1 = *reinterpret_cast<const f16x8*>(bp + 16 * 8);
    acc[0] = __builtin_amdgcn_mfma_f32_16x16x32_f16(av, b0, acc[0], 0, 0, 0);
    acc[1] = __builtin_amdgcn_mfma_f32_16x16x32_f16(av, b1, acc[1], 0, 0, 0);
  }
#pragma unroll
  for (int nf = 0; nf < 2; ++nf)
#pragma unroll
    for (int q = 0; q < 4; ++q) {
      int row = m0 + mg * 16 + quad * 4 + q;
      int col = r0 + ng * 32 + nf * 16 + lm;
      S[(size_t)row * R_RULES + col] = __expf(acc[nf][q]);
    }
}

// ---------------------------------------------------------------------------
// Kernel C: inv-denominator (normalization folded into main16).
// ---------------------------------------------------------------------------
__global__ __launch_bounds__(256) void anfis_den(
    const float* __restrict__ S, float* __restrict__ invden) {
  const int n = blockIdx.x * 4 + (threadIdx.x >> 6);
  const int lane = threadIdx.x & 63;
  float4 v = reinterpret_cast<const float4*>(S)[(size_t)n * 64 + lane];
  float s = (v.x + v.y) + (v.z + v.w);
#pragma unroll
  for (int off = 32; off; off >>= 1) s += __shfl_xor(s, off, 64);
  if (lane == 0) invden[n] = 1.0f / (s + 1e-8f);
}

// ---------------------------------------------------------------------------
// Kernel D (unchanged): permute coeffs fp32 -> fp16 Cp; flat per-g layout is
// Cp_g[i][j][rg]  (i*2048 + j*32 + rg), i in [0,136) zero-padded past 129.
// ---------------------------------------------------------------------------
__global__ __launch_bounds__(256) void anfis_prep(
    const float* __restrict__ coeffs, f16* __restrict__ Cp) {
  __shared__ alignas(16) f16 T[64 * 32];
  const int i = blockIdx.x;
  const int g = blockIdx.y;
  const int tid = threadIdx.x;
  const int rg = tid & 31;
  const int jb = tid >> 5;
  if (i < 129) {
    const float* src = coeffs + ((size_t)(g * 32 + rg) * 129 + i) * 64 + jb * 8;
    float4 a = reinterpret_cast<const float4*>(src)[0];
    float4 b = reinterpret_cast<const float4*>(src)[1];
    T[(jb * 8 + 0) * 32 + rg] = (f16)a.x;
    T[(jb * 8 + 1) * 32 + rg] = (f16)a.y;
    T[(jb * 8 + 2) * 32 + rg] = (f16)a.z;
    T[(jb * 8 + 3) * 32 + rg] = (f16)a.w;
    T[(jb * 8 + 4) * 32 + rg] = (f16)b.x;
    T[(jb * 8 + 5) * 32 + rg] = (f16)b.y;
    T[(jb * 8 + 6) * 32 + rg] = (f16)b.z;
    T[(jb * 8 + 7) * 32 + rg] = (f16)b.w;
  } else {
#pragma unroll
    for (int q = 0; q < 8; ++q) T[(jb * 8 + q) * 32 + rg] = (f16)0.0f;
  }
  __syncthreads();
  f16x8* dst = reinterpret_cast<f16x8*>(
      Cp + (((size_t)g * NCHUNK + (i >> 3)) * CH_I + (i & 7)) * 2048);
  dst[tid] = reinterpret_cast<const f16x8*>(T)[tid];
}

// ---------------------------------------------------------------------------
// Kernel E v3: rules GEMM, LDS-staged B (restored from R3) with
//  (a) no-mg-dup wave layout: wave w owns j-quadrant w*16..+15 across all
//      64 m rows -> B LDS reads halve (1 ds_read_b128 per ii per wave);
//  (b) 16KB chunks (4 i-rows) -> 33.8KB LDS -> 4 blocks/CU (vs 2), drains
//      hidden by co-resident blocks.  Normalization folded (pf = S*invden).
// ---------------------------------------------------------------------------
__global__ __launch_bounds__(256, 4) void anfis_main16(
    const float* __restrict__ X, const float* __restrict__ S,
    const float* __restrict__ invden, const f16* __restrict__ Cp,
    float* __restrict__ part) {
  __shared__ alignas(16) f16 Xs[64 * KPAD];          // [m][i]  17408 B
  __shared__ alignas(16) f16 Bs[CH4 * 64 * 32];      // [ii][j][rg] 16384 B
  const int tid = threadIdx.x;
  const int g = blockIdx.x & 7;
  const int m0 = (blockIdx.x >> 3) * 64;
  const int w = tid >> 6, lane = tid & 63;
  const int lm = lane & 15, quad = lane >> 4;

  // ---- stage X tile -> fp16 [m][KPAD], bias row, zero pad ----
#pragma unroll
  for (int it = 0; it < 8; ++it) {
    int fi = tid + (it << 8);
    int m = fi >> 5, k4 = (fi & 31) << 2;
    float4 v = reinterpret_cast<const float4*>(X)[(size_t)(m0 + m) * 32 + (fi & 31)];
    f16x4 h = {(f16)v.x, (f16)v.y, (f16)v.z, (f16)v.w};
    *reinterpret_cast<f16x4*>(&Xs[m * KPAD + k4]) = h;
  }
  if (tid < 64) {
    f16x8 bias = {};
    bias[0] = (f16)1.0f;
    *reinterpret_cast<f16x8*>(&Xs[tid * KPAD + 128]) = bias;
  }

  // ---- p-fragments: 4 m-frags, 8 rules each (quad*8..+7), S*invden ----
  union F8 { f16x8 v; f16x2 h[4]; };
  F8 pf[4];
#pragma unroll
  for (int mf = 0; mf < 4; ++mf) {
    int row = m0 + mf * 16 + lm;
    const float invd = invden[row];
    const float* pp = S + (size_t)row * R_RULES + g * 32 + quad * 8;
    float4 p0 = reinterpret_cast<const float4*>(pp)[0];
    float4 p1 = reinterpret_cast<const float4*>(pp)[1];
    pf[mf].h[0] = f16x2{(f16)(p0.x * invd), (f16)(p0.y * invd)};
    pf[mf].h[1] = f16x2{(f16)(p0.z * invd), (f16)(p0.w * invd)};
    pf[mf].h[2] = f16x2{(f16)(p1.x * invd), (f16)(p1.y * invd)};
    pf[mf].h[3] = f16x2{(f16)(p1.z * invd), (f16)(p1.w * invd)};
  }

  f32x4 acc[4] = {};
  const char* cpg = (const char*)Cp + (size_t)g * KPAD * 4096;  // g-slice

  for (int c = 0; c < NCH4; ++c) {
    __syncthreads();                           // prev chunk's compute done
    const char* gsrc = cpg + (size_t)c * 16384;
#pragma unroll
    for (int it = 0; it < 4; ++it) {
      int off = (it << 12) + (w << 10);        // wave-uniform LDS base
      __builtin_amdgcn_global_load_lds(
          (const __attribute__((address_space(1))) unsigned int*)(gsrc + off + lane * 16),
          (__attribute__((address_space(3))) unsigned int*)((char*)Bs + off),
          16, 0, 0);
    }
    __syncthreads();                           // loads drained
    // X values for this chunk: 4 i per m-frag row
    f16x4 xv[4];
#pragma unroll
    for (int mf = 0; mf < 4; ++mf)
      xv[mf] = *reinterpret_cast<const f16x4*>(&Xs[(mf * 16 + lm) * KPAD + c * 4]);
#pragma unroll
    for (int ii = 0; ii < CH4; ++ii) {
      f16x8 b = *reinterpret_cast<const f16x8*>(
          &Bs[(ii * 64 + w * 16 + lm) * 32 + quad * 8]);
#pragma unroll
      for (int mf = 0; mf < 4; ++mf) {
        f16 xvv = xv[mf][ii];
        f16x2 xd = {xvv, xvv};
        F8 a;
        a.h[0] = pf[mf].h[0] * xd;
        a.h[1] = pf[mf].h[1] * xd;
        a.h[2] = pf[mf].h[2] * xd;
        a.h[3] = pf[mf].h[3] * xd;
        acc[mf] = __builtin_amdgcn_mfma_f32_16x16x32_f16(a.v, b, acc[mf], 0, 0, 0);
      }
    }
  }

  // ---- epilogue: C/D layout col=lane&15, row=quad*4+reg ----
#pragma unroll
  for (int mf = 0; mf < 4; ++mf)
#pragma unroll
    for (int q = 0; q < 4; ++q) {
      int row = m0 + mf * 16 + quad * 4 + q;
      int col = w * 16 + lm;
      part[((size_t)g * N_SAMPLES + row) * O_OUT + col] = acc[mf][q];
    }
}

// ---------------------------------------------------------------------------
// Kernel F (unchanged): sum 8 group partials + softmax over 64 outputs.
// ---------------------------------------------------------------------------
__global__ __launch_bounds__(256) void anfis_out(
    const float* __restrict__ part, float* __restrict__ out) {
  const int n = blockIdx.x * 4 + (threadIdx.x >> 6);
  const int lane = threadIdx.x & 63;
  const size_t stride = (size_t)N_SAMPLES * O_OUT;
  const float* p0 = part + (size_t)n * O_OUT + lane;
  float v = 0.f;
#pragma unroll
  for (int gg = 0; gg < 8; ++gg) v += p0[gg * stride];
  float mx = v;
#pragma unroll
  for (int off = 32; off; off >>= 1) mx = fmaxf(mx, __shfl_xor(mx, off, 64));
  float e = __expf(v - mx);
  float s = e;
#pragma unroll
  for (int off = 32; off; off >>= 1) s += __shfl_xor(s, off, 64);
  out[(size_t)n * O_OUT + lane] = e / s;
}

extern "C" void kernel_launch(void* const* d_in, const int* in_sizes, int n_in,
                              void* d_out, int out_size, void* d_ws, size_t ws_size,
                              hipStream_t stream) {
  const float* X       = (const float*)d_in[0];
  const float* centers = (const float*)d_in[1];
  const float* sigmas  = (const float*)d_in[2];
  const float* coeffs  = (const float*)d_in[3];
  float* out = (float*)d_out;

  float* S    = (float*)d_ws;                                   // 4 MB
  float* part = S + (size_t)N_SAMPLES * R_RULES;                // 8 MB
  f16*   Cp   = (f16*)(part + (size_t)NGROUPS * N_SAMPLES * O_OUT);
  f16*   Bext = Cp + (size_t)NGROUPS * NCHUNK * CH_I * 2048;    // 400 KB
  float* invden = (float*)(Bext + (size_t)100 * 256 * 8);       // 16 KB

  anfis_prep2<<<R_RULES, 128, 0, stream>>>(centers, sigmas, Bext);
  anfis_prep<<<dim3(KPAD, NGROUPS), 256, 0, stream>>>(coeffs, Cp);
  anfis_s16<<<256, 512, 0, stream>>>(X, Bext, S);
  anfis_den<<<N_SAMPLES / 4, 256, 0, stream>>>(S, invden);
  anfis_main16<<<512, 256, 0, stream>>>(X, S, invden, Cp, part);
  anfis_out<<<N_SAMPLES / 4, 256, 0, stream>>>(part, out);
}

// Round 6
// 104.326 us; speedup vs baseline: 1.1659x; 1.1029x over previous
//
#include <hip/hip_runtime.h>

#define N_SAMPLES 4096
#define D_IN      128
#define R_RULES   256
#define O_OUT     64
#define KPAD      136
#define NCHUNK    17   // main16 k-chunks (8 i each)
#define CH_I      8
#define NGROUPS   8

typedef _Float16 f16;
typedef _Float16 f16x2 __attribute__((ext_vector_type(2)));
typedef _Float16 f16x4 __attribute__((ext_vector_type(4)));
typedef _Float16 f16x8 __attribute__((ext_vector_type(8)));
typedef float    f32x4 __attribute__((ext_vector_type(4)));

// ---------------------------------------------------------------------------
// Kernel 1: fused prep.  Blocks [0,1088): permute coeffs fp32 -> fp16
// Cp[g][i][j][rg] (i zero-padded past 129).  Blocks [1088,1216): build Bext
// for the strengths GEMM (Markidis hi/lo split), 2 rules per block.
// ---------------------------------------------------------------------------
__global__ __launch_bounds__(256) void anfis_prep_all(
    const float* __restrict__ coeffs, const float* __restrict__ centers,
    const float* __restrict__ sigmas, f16* __restrict__ Cp,
    f16* __restrict__ Bext) {
  __shared__ alignas(16) f16 T[64 * 32];
  __shared__ float red[4];
  const int bid = blockIdx.x;
  const int tid = threadIdx.x;

  if (bid < 1088) {                       // ---- coeffs permute ----
    const int g = bid / 136;
    const int i = bid - g * 136;
    const int rg = tid & 31;
    const int jb = tid >> 5;
    if (i < 129) {
      const float* src = coeffs + ((size_t)(g * 32 + rg) * 129 + i) * 64 + jb * 8;
      float4 a = reinterpret_cast<const float4*>(src)[0];
      float4 b = reinterpret_cast<const float4*>(src)[1];
      T[(jb * 8 + 0) * 32 + rg] = (f16)a.x;
      T[(jb * 8 + 1) * 32 + rg] = (f16)a.y;
      T[(jb * 8 + 2) * 32 + rg] = (f16)a.z;
      T[(jb * 8 + 3) * 32 + rg] = (f16)a.w;
      T[(jb * 8 + 4) * 32 + rg] = (f16)b.x;
      T[(jb * 8 + 5) * 32 + rg] = (f16)b.y;
      T[(jb * 8 + 6) * 32 + rg] = (f16)b.z;
      T[(jb * 8 + 7) * 32 + rg] = (f16)b.w;
    } else {
#pragma unroll
      for (int q = 0; q < 8; ++q) T[(jb * 8 + q) * 32 + rg] = (f16)0.0f;
    }
    __syncthreads();
    f16x8* dst = reinterpret_cast<f16x8*>(Cp + ((size_t)g * KPAD + i) * 2048);
    dst[tid] = reinterpret_cast<const f16x8*>(T)[tid];
  } else {                                // ---- Bext build (2 rules) ----
    const int sub = tid >> 7;             // 0/1: which rule of the pair
    const int d = tid & 127;
    const int r = ((bid - 1088) << 1) + sub;
    const float c = centers[(size_t)r * 128 + d];
    const float s = sigmas[(size_t)r * 128 + d];
    const float iv = 0.5f / (s * s);
    const float b1 = -iv;
    const float b2 = 2.0f * c * iv;
    f16 b1h = (f16)b1; f16 b1l = (f16)(b1 - (float)b1h);
    f16 b2h = (f16)b2; f16 b2l = (f16)(b2 - (float)b2h);
    auto put = [&](int k, f16 v) {
      Bext[((size_t)(k >> 3) * 256 + r) * 8 + (k & 7)] = v;
    };
    put(d, b1h);
    put(128 + d, b1l);
    put(256 + d, b1h);
    put(384 + d, b2h);
    put(512 + d, b2l);
    put(640 + d, b2h);
    float p = -c * c * iv;
#pragma unroll
    for (int off = 32; off; off >>= 1) p += __shfl_xor(p, off, 64);
    if ((tid & 63) == 0) red[tid >> 6] = p;
    __syncthreads();
    if (d < 30) put(770 + d, (f16)0.0f);
    if (d == 0) {
      float k2 = red[sub * 2] + red[sub * 2 + 1];
      f16 h = (f16)k2; f16 l = (f16)(k2 - (float)h);
      put(768, h);
      put(769, l);
    }
  }
}

// ---------------------------------------------------------------------------
// Kernel 2: strengths + normalization fused.  Block = 16 m-rows x all 256
// rules (8 waves, wave w = 16m x 32r).  Barrier-free MFMA k-loop (Markidis
// split, K=800), then in-block row-sum reduction and direct store of
// NORMALIZED fp16 P[n][r].  No fp32 S, no separate den pass.
// ---------------------------------------------------------------------------
__global__ __launch_bounds__(512) void anfis_s16n(
    const float* __restrict__ X, const f16* __restrict__ Bext,
    f16* __restrict__ P) {
  __shared__ alignas(16) f16 Xq[16 * 512];   // [m][plane*128+d], 16 KB
  __shared__ float rowsum[16][8];
  const int tid = threadIdx.x;
  const int m0 = blockIdx.x * 16;
  const int w = tid >> 6, lane = tid & 63;
  const int lm = lane & 15, quad = lane >> 4;

  if (tid < 256) {  // stage: one (m, d-oct) task per thread
    int m = tid >> 4, oct = tid & 15;
    const float* src = X + (size_t)(m0 + m) * 128 + oct * 8;
    float4 a = reinterpret_cast<const float4*>(src)[0];
    float4 b = reinterpret_cast<const float4*>(src)[1];
    float xs[8] = {a.x, a.y, a.z, a.w, b.x, b.y, b.z, b.w};
    f16x8 vh, vl, v2h, v2l;
#pragma unroll
    for (int q = 0; q < 8; ++q) {
      float x = xs[q];
      f16 h = (f16)x;   f16 l = (f16)(x - (float)h);
      float x2 = x * x;
      f16 h2 = (f16)x2; f16 l2 = (f16)(x2 - (float)h2);
      vh[q] = h; vl[q] = l; v2h[q] = h2; v2l[q] = l2;
    }
    f16x8* row = reinterpret_cast<f16x8*>(&Xq[m * 512]);
    int sw = m & 7;
    row[(0 * 16 + oct) ^ sw] = v2h;
    row[(1 * 16 + oct) ^ sw] = v2l;
    row[(2 * 16 + oct) ^ sw] = vh;
    row[(3 * 16 + oct) ^ sw] = vl;
  }
  __syncthreads();

  f32x4 acc[2] = {};
  const f16x8* arow = reinterpret_cast<const f16x8*>(&Xq[lm * 512]);
  const int asw = lm & 7;
  const int col0 = w * 32 + lm;

#pragma unroll
  for (int t = 0; t < 24; ++t) {
    const int seg = t >> 2;
    const int plane = (seg < 2) ? 0 : (seg == 2) ? 1 : (seg < 5) ? 2 : 3;
    const int o = t * 4 + quad;
    f16x8 av = arow[(plane * 16 + (o & 15)) ^ asw];
    const f16* bp = Bext + ((size_t)o * 256 + col0) * 8;
    f16x8 b0 = *reinterpret_cast<const f16x8*>(bp);
    f16x8 b1 = *reinterpret_cast<const f16x8*>(bp + 16 * 8);
    acc[0] = __builtin_amdgcn_mfma_f32_16x16x32_f16(av, b0, acc[0], 0, 0, 0);
    acc[1] = __builtin_amdgcn_mfma_f32_16x16x32_f16(av, b1, acc[1], 0, 0, 0);
  }
  {  // bias rows k=768,769
    f16x8 av = {};
    if (quad == 0) { av[0] = (f16)1.0f; av[1] = (f16)1.0f; }
    const int o = 96 + quad;
    const f16* bp = Bext + ((size_t)o * 256 + col0) * 8;
    f16x8 b0 = *reinterpret_cast<const f16x8*>(bp);
    f16x8 b1 = *reinterpret_cast<const f16x8*>(bp + 16 * 8);
    acc[0] = __builtin_amdgcn_mfma_f32_16x16x32_f16(av, b0, acc[0], 0, 0, 0);
    acc[1] = __builtin_amdgcn_mfma_f32_16x16x32_f16(av, b1, acc[1], 0, 0, 0);
  }

  // exp, then block-level row sums over all 256 rules
  float e[2][4];
#pragma unroll
  for (int nf = 0; nf < 2; ++nf)
#pragma unroll
    for (int q = 0; q < 4; ++q) e[nf][q] = __expf(acc[nf][q]);

  float rp[4];
#pragma unroll
  for (int q = 0; q < 4; ++q) {
    rp[q] = e[0][q] + e[1][q];
#pragma unroll
    for (int msk = 1; msk < 16; msk <<= 1) rp[q] += __shfl_xor(rp[q], msk, 64);
  }
  if (lm == 0)
#pragma unroll
    for (int q = 0; q < 4; ++q) rowsum[quad * 4 + q][w] = rp[q];
  __syncthreads();

#pragma unroll
  for (int q = 0; q < 4; ++q) {
    const int row = quad * 4 + q;
    float s8 = 0.f;
#pragma unroll
    for (int w2 = 0; w2 < 8; ++w2) s8 += rowsum[row][w2];
    const float inv = 1.0f / (s8 + 1e-8f);
#pragma unroll
    for (int nf = 0; nf < 2; ++nf)
      P[(size_t)(m0 + row) * R_RULES + w * 32 + nf * 16 + lm] =
          (f16)(e[nf][q] * inv);
  }
}

// ---------------------------------------------------------------------------
// Kernel 3: rules GEMM — EXACT R3 structure (109.4µs-proven): LDS-staged B
// via global_load_lds width-16, 17 chunks of 8 i, wave layout 2mg x 2ng.
// Only change: pf loads directly from normalized fp16 P (one f16x8).
// ---------------------------------------------------------------------------
__global__ __launch_bounds__(256) void anfis_main16(
    const float* __restrict__ X, const f16* __restrict__ P,
    const f16* __restrict__ Cp, float* __restrict__ part) {
  __shared__ alignas(16) f16 Xs[64 * KPAD];          // [m][i], 17408 B
  __shared__ alignas(16) f16 Bs[CH_I * 64 * 32];     // [ii][j][rg] 32768 B
  const int tid = threadIdx.x;
  const int g = blockIdx.x & 7;
  const int m0 = (blockIdx.x >> 3) * 64;
  const int w = tid >> 6, lane = tid & 63;
  const int mg = w >> 1, ng = w & 1;
  const int lm = lane & 15, quad = lane >> 4;

#pragma unroll
  for (int it = 0; it < 8; ++it) {
    int fi = tid + (it << 8);
    int m = fi >> 5, k4 = (fi & 31) << 2;
    float4 v = reinterpret_cast<const float4*>(X)[(size_t)(m0 + m) * 32 + (fi & 31)];
    f16x4 h = {(f16)v.x, (f16)v.y, (f16)v.z, (f16)v.w};
    *reinterpret_cast<f16x4*>(&Xs[m * KPAD + k4]) = h;
  }
  if (tid < 64) {
    f16x8 bias = {};
    bias[0] = (f16)1.0f;
    *reinterpret_cast<f16x8*>(&Xs[tid * KPAD + 128]) = bias;
  }

  union F8 { f16x8 v; f16x2 h[4]; };
  F8 pf[2];
#pragma unroll
  for (int mf = 0; mf < 2; ++mf) {
    int row = m0 + mg * 32 + mf * 16 + lm;
    pf[mf].v = *reinterpret_cast<const f16x8*>(
        &P[(size_t)row * R_RULES + g * 32 + quad * 8]);
  }

  f32x4 acc[2][2] = {};
  const char* cpg = (const char*)Cp + (size_t)g * KPAD * 4096;

  for (int c = 0; c < NCHUNK; ++c) {
    __syncthreads();
    const char* gsrc = cpg + (size_t)c * 32768;
#pragma unroll
    for (int it = 0; it < 8; ++it) {
      int off = (it << 12) + (w << 10);
      __builtin_amdgcn_global_load_lds(
          (const __attribute__((address_space(1))) unsigned int*)(gsrc + off + lane * 16),
          (__attribute__((address_space(3))) unsigned int*)((char*)Bs + off),
          16, 0, 0);
    }
    __syncthreads();
    f16x8 xv[2];
    xv[0] = *reinterpret_cast<const f16x8*>(&Xs[(mg * 32 + lm) * KPAD + c * 8]);
    xv[1] = *reinterpret_cast<const f16x8*>(&Xs[(mg * 32 + 16 + lm) * KPAD + c * 8]);
#pragma unroll
    for (int ii = 0; ii < CH_I; ++ii) {
      F8 a[2];
#pragma unroll
      for (int mf = 0; mf < 2; ++mf) {
        f16 xvv = xv[mf][ii];
        f16x2 xd = {xvv, xvv};
        a[mf].h[0] = pf[mf].h[0] * xd;
        a[mf].h[1] = pf[mf].h[1] * xd;
        a[mf].h[2] = pf[mf].h[2] * xd;
        a[mf].h[3] = pf[mf].h[3] * xd;
      }
      const f16* brow = &Bs[(ii * 64 + ng * 32 + lm) * 32 + quad * 8];
      f16x8 b0 = *reinterpret_cast<const f16x8*>(brow);
      f16x8 b1 = *reinterpret_cast<const f16x8*>(brow + 16 * 32);
      acc[0][0] = __builtin_amdgcn_mfma_f32_16x16x32_f16(a[0].v, b0, acc[0][0], 0, 0, 0);
      acc[0][1] = __builtin_amdgcn_mfma_f32_16x16x32_f16(a[0].v, b1, acc[0][1], 0, 0, 0);
      acc[1][0] = __builtin_amdgcn_mfma_f32_16x16x32_f16(a[1].v, b0, acc[1][0], 0, 0, 0);
      acc[1][1] = __builtin_amdgcn_mfma_f32_16x16x32_f16(a[1].v, b1, acc[1][1], 0, 0, 0);
    }
  }

#pragma unroll
  for (int mf = 0; mf < 2; ++mf)
#pragma unroll
    for (int nf = 0; nf < 2; ++nf)
#pragma unroll
      for (int q = 0; q < 4; ++q) {
        int row = m0 + mg * 32 + mf * 16 + quad * 4 + q;
        int col = ng * 32 + nf * 16 + lm;
        part[((size_t)g * N_SAMPLES + row) * O_OUT + col] = acc[mf][nf][q];
      }
}

// ---------------------------------------------------------------------------
// Kernel 4: sum 8 group partials + softmax over 64 outputs.
// ---------------------------------------------------------------------------
__global__ __launch_bounds__(256) void anfis_out(
    const float* __restrict__ part, float* __restrict__ out) {
  const int n = blockIdx.x * 4 + (threadIdx.x >> 6);
  const int lane = threadIdx.x & 63;
  const size_t stride = (size_t)N_SAMPLES * O_OUT;
  const float* p0 = part + (size_t)n * O_OUT + lane;
  float v = 0.f;
#pragma unroll
  for (int gg = 0; gg < 8; ++gg) v += p0[gg * stride];
  float mx = v;
#pragma unroll
  for (int off = 32; off; off >>= 1) mx = fmaxf(mx, __shfl_xor(mx, off, 64));
  float e = __expf(v - mx);
  float s = e;
#pragma unroll
  for (int off = 32; off; off >>= 1) s += __shfl_xor(s, off, 64);
  out[(size_t)n * O_OUT + lane] = e / s;
}

extern "C" void kernel_launch(void* const* d_in, const int* in_sizes, int n_in,
                              void* d_out, int out_size, void* d_ws, size_t ws_size,
                              hipStream_t stream) {
  const float* X       = (const float*)d_in[0];
  const float* centers = (const float*)d_in[1];
  const float* sigmas  = (const float*)d_in[2];
  const float* coeffs  = (const float*)d_in[3];
  float* out = (float*)d_out;

  float* part = (float*)d_ws;                                   // 8 MB
  f16*   Cp   = (f16*)(part + (size_t)NGROUPS * N_SAMPLES * O_OUT);
  f16*   Bext = Cp + (size_t)NGROUPS * KPAD * 2048;             // 400 KB
  f16*   P    = Bext + (size_t)100 * 256 * 8;                   // 2 MB

  anfis_prep_all<<<1088 + 128, 256, 0, stream>>>(coeffs, centers, sigmas, Cp, Bext);
  anfis_s16n<<<N_SAMPLES / 16, 512, 0, stream>>>(X, Bext, P);
  anfis_main16<<<512, 256, 0, stream>>>(X, P, Cp, part);
  anfis_out<<<N_SAMPLES / 4, 256, 0, stream>>>(part, out);
}